// Round 1
// baseline (234.051 us; speedup 1.0000x reference)
//
#include <hip/hip_runtime.h>
#include <hip/hip_bf16.h>
#include <math.h>

typedef __bf16 bf16_t;
typedef __bf16 bf16x8 __attribute__((ext_vector_type(8)));
typedef __bf16 bf16x4 __attribute__((ext_vector_type(4)));
typedef float  f32x4  __attribute__((ext_vector_type(4)));

#define D_MODEL 1024
#define NH      16
#define DH      64
#define LSEQ    2048
#define NROWS   4096          // B*L = 2*2048
#define LOG2E   1.44269504088896340736f

// ---------------------------------------------------------------- helpers
__device__ __forceinline__ void gld_lds16(bf16_t* lds, const bf16_t* g) {
  // async global->LDS, 16B per lane; LDS dest must be wave-uniform base + lane*16
  __builtin_amdgcn_global_load_lds(
      (__attribute__((address_space(1))) void*)(unsigned long long)g,
      (__attribute__((address_space(3))) void*)lds,
      16, 0, 0);
}

// ---------------------------------------------------------------- convert
__global__ __launch_bounds__(256)
void k_cvt(const float* __restrict__ in, bf16_t* __restrict__ out, int n4) {
  int i = blockIdx.x * blockDim.x + threadIdx.x;
  int stride = gridDim.x * blockDim.x;
  for (; i < n4; i += stride) {
    float4 v = ((const float4*)in)[i];
    bf16x4 o = { (bf16_t)v.x, (bf16_t)v.y, (bf16_t)v.z, (bf16_t)v.w };
    ((bf16x4*)out)[i] = o;
  }
}

// ---------------------------------------------------------------- GEMM  C = A * B^T
// A: Mx K row-major bf16, B: N x K row-major bf16 (i.e. B^T input form).
// 128x128 tile, BK=32, 4 waves (2x2), each wave 64x64 = 4x4 16x16 frags.
// MODE 0: plain f32 store to Fo.   MODE 1: fused RoPE epilogue -> Qo/Ko/Vo (N=3072).
template<int MODE>
__global__ __launch_bounds__(256)
void k_gemm(const bf16_t* __restrict__ A, const bf16_t* __restrict__ B,
            int N, int K,
            float* __restrict__ Fo,
            bf16_t* __restrict__ Qo, bf16_t* __restrict__ Ko, bf16_t* __restrict__ Vo)
{
  __shared__ bf16_t As[128 * 32];
  __shared__ bf16_t Bs[128 * 32];
  const int tid  = threadIdx.x;
  const int wave = tid >> 6, lane = tid & 63;
  const int hi   = lane >> 4, lo = lane & 15;
  const int m0   = blockIdx.y * 128, n0 = blockIdx.x * 128;
  const int wr   = (wave >> 1) * 64, wc = (wave & 1) * 64;

  f32x4 acc[4][4] = {};

  for (int k0 = 0; k0 < K; k0 += 32) {
    __syncthreads();
    {
      int id = tid;
      gld_lds16(As + id * 8, A + (size_t)(m0 + (id >> 2)) * K + k0 + (id & 3) * 8);
      gld_lds16(Bs + id * 8, B + (size_t)(n0 + (id >> 2)) * K + k0 + (id & 3) * 8);
      id = tid + 256;
      gld_lds16(As + id * 8, A + (size_t)(m0 + (id >> 2)) * K + k0 + (id & 3) * 8);
      gld_lds16(Bs + id * 8, B + (size_t)(n0 + (id >> 2)) * K + k0 + (id & 3) * 8);
    }
    __syncthreads();   // compiler drains vmcnt before s_barrier

    bf16x8 a[4], b[4];
    #pragma unroll
    for (int mi = 0; mi < 4; mi++)
      a[mi] = *(const bf16x8*)(As + (wr + mi * 16 + lo) * 32 + hi * 8);
    #pragma unroll
    for (int ni = 0; ni < 4; ni++)
      b[ni] = *(const bf16x8*)(Bs + (wc + ni * 16 + lo) * 32 + hi * 8);
    #pragma unroll
    for (int mi = 0; mi < 4; mi++)
      #pragma unroll
      for (int ni = 0; ni < 4; ni++)
        acc[mi][ni] = __builtin_amdgcn_mfma_f32_16x16x32_bf16(a[mi], b[ni], acc[mi][ni], 0, 0, 0);
  }

  if constexpr (MODE == 0) {
    #pragma unroll
    for (int mi = 0; mi < 4; mi++)
      #pragma unroll
      for (int ni = 0; ni < 4; ni++)
        #pragma unroll
        for (int r = 0; r < 4; r++) {
          int row = m0 + wr + mi * 16 + hi * 4 + r;
          int col = n0 + wc + ni * 16 + lo;
          Fo[(size_t)row * N + col] = acc[mi][ni][r];
        }
  } else {
    // RoPE epilogue. col: [which(2b) | h(4b) | d(6b)], row: [b | l(11b)]
    #pragma unroll
    for (int mi = 0; mi < 4; mi++)
      #pragma unroll
      for (int ni = 0; ni < 4; ni++)
        #pragma unroll
        for (int r = 0; r < 4; r++) {
          float val  = acc[mi][ni][r];
          float part = __shfl_xor(val, 1, 64);   // partner head-dim (d^1)
          int row = m0 + wr + mi * 16 + hi * 4 + r;
          int col = n0 + wc + ni * 16 + lo;
          int which = col >> 10;
          int h = (col >> 6) & 15;
          int d = col & 63;
          int b = row >> 11, l = row & 2047;
          size_t oidx = ((size_t)(b * NH + h) * LSEQ + l) * DH + d;
          if (which == 2) {
            Vo[oidx] = (bf16_t)val;
          } else {
            int p = d >> 1;
            // freq = 10000^(-p/32); angle = l * freq   (matches jnp f32 tables)
            float freq = expf(-0.28782313662425575f * (float)p);
            float ang  = (float)l * freq;
            float s, c;
            sincosf(ang, &s, &c);
            float rot = (d & 1) ? (part * s + val * c) : (val * c - part * s);
            if (which == 0) rot *= 0.125f;       // fold 1/sqrt(DH) into Q
            (which == 0 ? Qo : Ko)[oidx] = (bf16_t)rot;
          }
        }
  }
}

// ---------------------------------------------------------------- flash attention
// Q,K,V: (B*H, L, DH) bf16 (Q pre-scaled by 1/8). O: (B, L, H*DH) bf16.
// Block: 4 waves, 64 q-rows (16 per wave). KV tile = 64 rows.
__global__ __launch_bounds__(256)
void k_attn(const bf16_t* __restrict__ Q, const bf16_t* __restrict__ K,
            const bf16_t* __restrict__ V, bf16_t* __restrict__ O)
{
  __shared__ bf16_t Kt[64 * 72];        // K rows, +8 pad -> 144B row stride
  __shared__ bf16_t Vt[64 * 72];        // V TRANSPOSED: Vt[d][s]
  __shared__ bf16_t Pb[4 * 16 * 72];    // per-wave P bounce buffer
  const int tid  = threadIdx.x;
  const int wave = tid >> 6, lane = tid & 63;
  const int hi   = lane >> 4, lo = lane & 15;
  const int qt = blockIdx.x, bh = blockIdx.y;

  const bf16_t* Qb = Q + (size_t)bh * LSEQ * DH;
  const bf16_t* Kb = K + (size_t)bh * LSEQ * DH;
  const bf16_t* Vb = V + (size_t)bh * LSEQ * DH;

  const int qrow = qt * 64 + wave * 16 + lo;
  bf16x8 qf0 = *(const bf16x8*)(Qb + (size_t)qrow * DH + hi * 8);
  bf16x8 qf1 = *(const bf16x8*)(Qb + (size_t)qrow * DH + 32 + hi * 8);

  f32x4 acc[4] = {};
  float mrun[4], lrun[4];
  #pragma unroll
  for (int r = 0; r < 4; r++) { mrun[r] = -INFINITY; lrun[r] = 0.f; }
  bf16_t* Pw = Pb + wave * 16 * 72;

  for (int s0 = 0; s0 < LSEQ; s0 += 64) {
    __syncthreads();
    // stage K tile (row-major, padded)
    #pragma unroll
    for (int it = 0; it < 2; it++) {
      int id = tid + it * 256;
      int r = id >> 3, ch = id & 7;
      *(bf16x8*)(Kt + r * 72 + ch * 8) =
          *(const bf16x8*)(Kb + (size_t)(s0 + r) * DH + ch * 8);
    }
    // stage V tile transposed
    #pragma unroll
    for (int it = 0; it < 2; it++) {
      int s  = tid & 63;
      int cd = (tid >> 6) + it * 4;
      bf16x8 vv = *(const bf16x8*)(Vb + (size_t)(s0 + s) * DH + cd * 8);
      #pragma unroll
      for (int j = 0; j < 8; j++) Vt[(cd * 8 + j) * 72 + s] = vv[j];
    }
    __syncthreads();

    // S = Q K^T  (16 q-rows x 64 s), C frag: col=s (lane&15), row=q (hi*4+reg)
    f32x4 sa[4] = {};
    #pragma unroll
    for (int sb = 0; sb < 4; sb++) {
      bf16x8 kb0 = *(const bf16x8*)(Kt + (sb * 16 + lo) * 72 + hi * 8);
      bf16x8 kb1 = *(const bf16x8*)(Kt + (sb * 16 + lo) * 72 + 32 + hi * 8);
      sa[sb] = __builtin_amdgcn_mfma_f32_16x16x32_bf16(qf0, kb0, sa[sb], 0, 0, 0);
      sa[sb] = __builtin_amdgcn_mfma_f32_16x16x32_bf16(qf1, kb1, sa[sb], 0, 0, 0);
    }

    // online softmax (row stats across the 16-lane column group)
    float mnew[4], scale_[4];
    #pragma unroll
    for (int r = 0; r < 4; r++) {
      float mx = fmaxf(fmaxf(sa[0][r], sa[1][r]), fmaxf(sa[2][r], sa[3][r]));
      #pragma unroll
      for (int msk = 1; msk < 16; msk <<= 1) mx = fmaxf(mx, __shfl_xor(mx, msk, 64));
      mnew[r]   = fmaxf(mrun[r], mx);
      scale_[r] = exp2f((mrun[r] - mnew[r]) * LOG2E);
      mrun[r]   = mnew[r];
    }
    float rs[4] = {0.f, 0.f, 0.f, 0.f};
    #pragma unroll
    for (int sb = 0; sb < 4; sb++)
      #pragma unroll
      for (int r = 0; r < 4; r++) {
        float p = exp2f((sa[sb][r] - mnew[r]) * LOG2E);
        sa[sb][r] = p;
        rs[r] += p;
      }
    #pragma unroll
    for (int r = 0; r < 4; r++) {
      #pragma unroll
      for (int msk = 1; msk < 16; msk <<= 1) rs[r] += __shfl_xor(rs[r], msk, 64);
      lrun[r] = lrun[r] * scale_[r] + rs[r];
    }
    #pragma unroll
    for (int nb = 0; nb < 4; nb++)
      #pragma unroll
      for (int r = 0; r < 4; r++) acc[nb][r] *= scale_[r];

    // P -> LDS (bf16), then re-read as PV A-fragments
    #pragma unroll
    for (int sb = 0; sb < 4; sb++)
      #pragma unroll
      for (int r = 0; r < 4; r++)
        Pw[(hi * 4 + r) * 72 + sb * 16 + lo] = (bf16_t)sa[sb][r];
    __syncthreads();

    bf16x8 pa0 = *(const bf16x8*)(Pw + lo * 72 + hi * 8);
    bf16x8 pa1 = *(const bf16x8*)(Pw + lo * 72 + 32 + hi * 8);
    #pragma unroll
    for (int nb = 0; nb < 4; nb++) {
      bf16x8 vb0 = *(const bf16x8*)(Vt + (nb * 16 + lo) * 72 + hi * 8);
      bf16x8 vb1 = *(const bf16x8*)(Vt + (nb * 16 + lo) * 72 + 32 + hi * 8);
      acc[nb] = __builtin_amdgcn_mfma_f32_16x16x32_bf16(pa0, vb0, acc[nb], 0, 0, 0);
      acc[nb] = __builtin_amdgcn_mfma_f32_16x16x32_bf16(pa1, vb1, acc[nb], 0, 0, 0);
    }
  }

  // epilogue: normalize, store to (B, L, H*DH)
  const int b = bh >> 4, h = bh & 15;
  #pragma unroll
  for (int r = 0; r < 4; r++) {
    float inv = 1.0f / lrun[r];
    int l = qt * 64 + wave * 16 + hi * 4 + r;
    #pragma unroll
    for (int nb = 0; nb < 4; nb++)
      O[((size_t)(b * LSEQ + l)) * D_MODEL + h * DH + nb * 16 + lo] =
          (bf16_t)(acc[nb][r] * inv);
  }
}

// ---------------------------------------------------------------- launch
extern "C" void kernel_launch(void* const* d_in, const int* in_sizes, int n_in,
                              void* d_out, int out_size, void* d_ws, size_t ws_size,
                              hipStream_t stream)
{
  (void)in_sizes; (void)n_in; (void)out_size; (void)ws_size;
  const float* x  = (const float*)d_in[0];
  const float* Wq = (const float*)d_in[1];
  const float* Wk = (const float*)d_in[2];
  const float* Wv = (const float*)d_in[3];
  const float* Wo = (const float*)d_in[4];
  float* out = (float*)d_out;

  bf16_t* ws   = (bf16_t*)d_ws;
  bf16_t* xb   = ws;                                        // 4096*1024
  bf16_t* wqkv = xb + (size_t)NROWS * D_MODEL;              // 3*1024*1024
  bf16_t* wo   = wqkv + (size_t)3 * D_MODEL * D_MODEL;      // 1024*1024
  bf16_t* Qw   = wo + (size_t)D_MODEL * D_MODEL;            // (BH, L, DH)
  bf16_t* Kw   = Qw + (size_t)NROWS * D_MODEL;
  bf16_t* Vw   = Kw + (size_t)NROWS * D_MODEL;
  bf16_t* Aw   = Vw + (size_t)NROWS * D_MODEL;              // (B*L, D_MODEL)

  const int WN = D_MODEL * D_MODEL;  // 1M elements

  k_cvt<<<1024, 256, 0, stream>>>(x, xb, NROWS * D_MODEL / 4);
  k_cvt<<<512, 256, 0, stream>>>(Wq, wqkv, WN / 4);
  k_cvt<<<512, 256, 0, stream>>>(Wk, wqkv + (size_t)WN, WN / 4);
  k_cvt<<<512, 256, 0, stream>>>(Wv, wqkv + (size_t)2 * WN, WN / 4);
  k_cvt<<<512, 256, 0, stream>>>(Wo, wo, WN / 4);

  dim3 g1(3072 / 128, 4096 / 128);
  k_gemm<1><<<g1, 256, 0, stream>>>(xb, wqkv, 3072, 1024, nullptr, Qw, Kw, Vw);

  dim3 g2(LSEQ / 64, 32);   // (q-tiles, B*H)
  k_attn<<<g2, 256, 0, stream>>>(Qw, Kw, Vw, Aw);

  dim3 g3(1024 / 128, 4096 / 128);
  k_gemm<0><<<g3, 256, 0, stream>>>(Aw, wo, 1024, 1024, out, nullptr, nullptr, nullptr);
}